// Round 1
// baseline (250.685 us; speedup 1.0000x reference)
//
#include <hip/hip_runtime.h>
#include <hip/hip_bf16.h>

typedef __bf16 bf16;
typedef __attribute__((ext_vector_type(8))) __bf16 bf16x8;
typedef __attribute__((ext_vector_type(4))) __bf16 bf16x4;
typedef __attribute__((ext_vector_type(4))) float f32x4;

#define GLOAD_LDS16(g, l) __builtin_amdgcn_global_load_lds( \
    (const __attribute__((address_space(1))) void*)(g),     \
    (__attribute__((address_space(3))) void*)(l), 16, 0, 0)

constexpr int MTOT = 4096;   // BS*QLEN
constexpr int DIMC = 1024;
constexpr int QL   = 2048;
constexpr int NH   = 16;
constexpr int HD   = 64;

// ---------------- fp32 -> bf16 convert ----------------
__global__ void cvt_f32_bf16(const float* __restrict__ src, bf16* __restrict__ dst, int n) {
  int i = (blockIdx.x * blockDim.x + threadIdx.x) * 4;
  if (i < n) {
    float4 f = *reinterpret_cast<const float4*>(src + i);
    bf16x4 v;
    v[0] = (bf16)f.x; v[1] = (bf16)f.y; v[2] = (bf16)f.z; v[3] = (bf16)f.w;
    *reinterpret_cast<bf16x4*>(dst + i) = v;
  }
}

// ---------------- BT GEMM: C[m][n] = sum_k A[m][k]*B[n][k], C=(acc+bias)*scale ----
// A: [4096][1024] bf16, B: [1024][1024] bf16 (row-major, K contiguous = B^T input)
// 128x128 tile, BK=64, 256 threads (4 waves, 2x2 of 64x64), 16x16x32 bf16 MFMA.
// blockIdx.z selects weight/bias/dst (fused QKV); BF16OUT selects output dtype.
template<bool BF16OUT>
__global__ __launch_bounds__(256) void gemm_bt(
    const bf16* __restrict__ A,
    const bf16* __restrict__ W0, const bf16* __restrict__ W1, const bf16* __restrict__ W2,
    const float* __restrict__ b0, const float* __restrict__ b1, const float* __restrict__ b2,
    void* __restrict__ D0, void* __restrict__ D1, void* __restrict__ D2,
    float scale0)
{
  __shared__ __align__(16) bf16 As[128 * 64];
  __shared__ __align__(16) bf16 Bs[128 * 64];

  const bf16* Bm; const float* bias; void* D; float scale = 1.f;
  const int z = blockIdx.z;
  if (z == 0)      { Bm = W0; bias = b0; D = D0; scale = scale0; }
  else if (z == 1) { Bm = W1; bias = b1; D = D1; }
  else             { Bm = W2; bias = b2; D = D2; }

  const int tid  = threadIdx.x;
  const int w    = tid >> 6, lane = tid & 63;
  const int gm0  = blockIdx.x * 128, gn0 = blockIdx.y * 128;
  const int wr   = (w >> 1) * 64, wc = (w & 1) * 64;
  const int lr   = lane & 15;          // fragment row selector (A/B row)
  const int lk   = (lane >> 4) * 8;    // fragment k offset
  const int srow = (w << 3) + (lane >> 3);  // staging row within a 32-row pass
  const int scol = (lane & 7) * 8;          // staging col (elements)

  f32x4 acc[4][4] = {};

  for (int kt = 0; kt < DIMC / 64; ++kt) {
    __syncthreads();  // previous iteration's LDS reads complete
    const int k0 = kt * 64;
#pragma unroll
    for (int p = 0; p < 4; ++p) {
      const int r = p * 32 + srow;
      GLOAD_LDS16(A  + (size_t)(gm0 + r) * DIMC + k0 + scol, &As[(p * 32 + (w << 3)) * 64]);
      GLOAD_LDS16(Bm + (size_t)(gn0 + r) * DIMC + k0 + scol, &Bs[(p * 32 + (w << 3)) * 64]);
    }
    asm volatile("s_waitcnt vmcnt(0)" ::: "memory");
    __syncthreads();

#pragma unroll
    for (int kk = 0; kk < 2; ++kk) {
      bf16x8 af[4], bfv[4];
#pragma unroll
      for (int mf = 0; mf < 4; ++mf)
        af[mf] = *reinterpret_cast<const bf16x8*>(&As[(wr + mf * 16 + lr) * 64 + kk * 32 + lk]);
#pragma unroll
      for (int nf = 0; nf < 4; ++nf)
        bfv[nf] = *reinterpret_cast<const bf16x8*>(&Bs[(wc + nf * 16 + lr) * 64 + kk * 32 + lk]);
#pragma unroll
      for (int mf = 0; mf < 4; ++mf)
#pragma unroll
        for (int nf = 0; nf < 4; ++nf)
          acc[mf][nf] = __builtin_amdgcn_mfma_f32_16x16x32_bf16(af[mf], bfv[nf], acc[mf][nf], 0, 0, 0);
    }
  }

  const int orow = (lane >> 4) * 4;  // C row base: row=(lane>>4)*4+i, col=lane&15 (m89 layout)
#pragma unroll
  for (int mf = 0; mf < 4; ++mf) {
#pragma unroll
    for (int nf = 0; nf < 4; ++nf) {
      const int c = gn0 + wc + nf * 16 + lr;
      const float bv = bias[c];
#pragma unroll
      for (int i = 0; i < 4; ++i) {
        const int r = gm0 + wr + mf * 16 + orow + i;
        const float v = (acc[mf][nf][i] + bv) * scale;
        if constexpr (BF16OUT) ((bf16*)D)[(size_t)r * DIMC + c]  = (bf16)v;
        else                   ((float*)D)[(size_t)r * DIMC + c] = v;
      }
    }
  }
}

// ---------------- Flash attention ----------------
// grid (32 qtiles, 32 bh), 256 threads = 4 waves; wave w owns q rows [qt*64+w*16, +16).
// KV tiles of 64. K in padded LDS [64][72] (2-way bank alias = free); V transposed
// into Vt[64 d][72] so PV is a BT-GEMM; P staged per-wave in LDS for the A-operand.
__global__ __launch_bounds__(256) void attn_fwd(
    const bf16* __restrict__ Q, const bf16* __restrict__ K, const bf16* __restrict__ V,
    const float* __restrict__ mask, bf16* __restrict__ ctx)
{
  __shared__ __align__(16) bf16 Ks[64 * 72];
  __shared__ __align__(16) bf16 Vt[64 * 72];
  __shared__ __align__(16) bf16 Ps[4][16 * 72];

  const int tid = threadIdx.x, w = tid >> 6, lane = tid & 63;
  const int qt = blockIdx.x;            // 0..31
  const int bh = blockIdx.y;            // 0..31
  const int b = bh >> 4, h = bh & 15;
  const size_t rowbase = (size_t)b * QL;
  const int colbase = h * HD;
  const int lr = lane & 15, lk = (lane >> 4) * 8;

  // Q fragments (A operand), rows qt*64 + w*16 + (lane&15)
  bf16x8 aq[2];
  {
    const int qr = qt * 64 + w * 16 + lr;
    const bf16* qp = Q + (rowbase + qr) * DIMC + colbase + lk;
    aq[0] = *reinterpret_cast<const bf16x8*>(qp);
    aq[1] = *reinterpret_cast<const bf16x8*>(qp + 32);
  }

  float m_i[4], l_i[4];
  f32x4 acc_o[4] = {};
#pragma unroll
  for (int i = 0; i < 4; ++i) { m_i[i] = -INFINITY; l_i[i] = 0.f; }

  for (int t = 0; t < QL / 64; ++t) {
    const int kv0 = t * 64;

    // register-stage K and V tiles (64 rows x 64 cols, 16B chunks)
    bf16x8 kr[2], vr[2];
#pragma unroll
    for (int s = 0; s < 2; ++s) {
      const int ci = tid + s * 256;
      const int r = ci >> 3, c8 = ci & 7;
      kr[s] = *reinterpret_cast<const bf16x8*>(K + (rowbase + kv0 + r) * DIMC + colbase + c8 * 8);
      vr[s] = *reinterpret_cast<const bf16x8*>(V + (rowbase + kv0 + r) * DIMC + colbase + c8 * 8);
    }
    __syncthreads();  // previous tile's LDS reads complete
#pragma unroll
    for (int s = 0; s < 2; ++s) {
      const int ci = tid + s * 256;
      const int r = ci >> 3, c8 = ci & 7;
      *reinterpret_cast<bf16x8*>(&Ks[r * 72 + c8 * 8]) = kr[s];
#pragma unroll
      for (int j = 0; j < 8; ++j) Vt[(c8 * 8 + j) * 72 + r] = vr[s][j];
    }
    __syncthreads();

    // S = Q K^T  (per wave: 16 q-rows x 64 kv-cols)
    f32x4 sacc[4] = {};
#pragma unroll
    for (int kk = 0; kk < 2; ++kk) {
      bf16x8 bk[4];
#pragma unroll
      for (int nf = 0; nf < 4; ++nf)
        bk[nf] = *reinterpret_cast<const bf16x8*>(&Ks[(nf * 16 + lr) * 72 + kk * 32 + lk]);
#pragma unroll
      for (int nf = 0; nf < 4; ++nf)
        sacc[nf] = __builtin_amdgcn_mfma_f32_16x16x32_bf16(aq[kk], bk[nf], sacc[nf], 0, 0, 0);
    }

    float mk[4];
#pragma unroll
    for (int nf = 0; nf < 4; ++nf) mk[nf] = mask[b * QL + kv0 + nf * 16 + lr];

    // online softmax; row = (lane>>4)*4 + i, cols across lanes of the 16-lane group
#pragma unroll
    for (int i = 0; i < 4; ++i) {
      const float s0 = sacc[0][i] + mk[0], s1 = sacc[1][i] + mk[1];
      const float s2 = sacc[2][i] + mk[2], s3 = sacc[3][i] + mk[3];
      float mx = fmaxf(fmaxf(s0, s1), fmaxf(s2, s3));
#pragma unroll
      for (int off = 1; off < 16; off <<= 1) mx = fmaxf(mx, __shfl_xor(mx, off, 64));
      const float mnew = fmaxf(m_i[i], mx);
      const float alpha = __expf(m_i[i] - mnew);
      const float p0 = __expf(s0 - mnew), p1 = __expf(s1 - mnew);
      const float p2 = __expf(s2 - mnew), p3 = __expf(s3 - mnew);
      const int prow = (lane >> 4) * 4 + i;
      bf16* pp = &Ps[w][prow * 72 + lr];
      pp[0] = (bf16)p0; pp[16] = (bf16)p1; pp[32] = (bf16)p2; pp[48] = (bf16)p3;
      float rs = p0 + p1 + p2 + p3;
#pragma unroll
      for (int off = 1; off < 16; off <<= 1) rs += __shfl_xor(rs, off, 64);
      l_i[i] = l_i[i] * alpha + rs;
      m_i[i] = mnew;
#pragma unroll
      for (int df = 0; df < 4; ++df) acc_o[df][i] *= alpha;
    }

    // O += P V   (B operand = Vt rows = d)
#pragma unroll
    for (int kk = 0; kk < 2; ++kk) {
      const bf16x8 ap = *reinterpret_cast<const bf16x8*>(&Ps[w][lr * 72 + kk * 32 + lk]);
#pragma unroll
      for (int df = 0; df < 4; ++df) {
        const bf16x8 bv = *reinterpret_cast<const bf16x8*>(&Vt[(df * 16 + lr) * 72 + kk * 32 + lk]);
        acc_o[df] = __builtin_amdgcn_mfma_f32_16x16x32_bf16(ap, bv, acc_o[df], 0, 0, 0);
      }
    }
  }

  // epilogue: ctx[b*QL + r][h*64 + d] = acc/l
#pragma unroll
  for (int i = 0; i < 4; ++i) {
    const float inv = 1.0f / l_i[i];
    const int r = qt * 64 + w * 16 + (lane >> 4) * 4 + i;
#pragma unroll
    for (int df = 0; df < 4; ++df) {
      const int c = colbase + df * 16 + lr;
      ctx[(rowbase + r) * DIMC + c] = (bf16)(acc_o[df][i] * inv);
    }
  }
}

// ---------------- launch ----------------
extern "C" void kernel_launch(void* const* d_in, const int* in_sizes, int n_in,
                              void* d_out, int out_size, void* d_ws, size_t ws_size,
                              hipStream_t stream) {
  const float* x    = (const float*)d_in[0];
  const float* mask = (const float*)d_in[1];
  const float* qw = (const float*)d_in[2]; const float* qb = (const float*)d_in[3];
  const float* kw = (const float*)d_in[4]; const float* kb = (const float*)d_in[5];
  const float* vw = (const float*)d_in[6]; const float* vb = (const float*)d_in[7];
  const float* ow = (const float*)d_in[8]; const float* ob = (const float*)d_in[9];
  float* out = (float*)d_out;

  // workspace layout (bf16 elements), total 48 MB
  bf16* Xb  = (bf16*)d_ws;
  bf16* Wqb = Xb  + (size_t)MTOT * DIMC;
  bf16* Wkb = Wqb + (size_t)DIMC * DIMC;
  bf16* Wvb = Wkb + (size_t)DIMC * DIMC;
  bf16* Wob = Wvb + (size_t)DIMC * DIMC;
  bf16* Qb  = Wob + (size_t)DIMC * DIMC;
  bf16* Kb  = Qb  + (size_t)MTOT * DIMC;
  bf16* Vb  = Kb  + (size_t)MTOT * DIMC;
  bf16* Cb  = Vb  + (size_t)MTOT * DIMC;

  const int nX = MTOT * DIMC, nW = DIMC * DIMC;
  cvt_f32_bf16<<<(nX / 4 + 255) / 256, 256, 0, stream>>>(x,  Xb,  nX);
  cvt_f32_bf16<<<(nW / 4 + 255) / 256, 256, 0, stream>>>(qw, Wqb, nW);
  cvt_f32_bf16<<<(nW / 4 + 255) / 256, 256, 0, stream>>>(kw, Wkb, nW);
  cvt_f32_bf16<<<(nW / 4 + 255) / 256, 256, 0, stream>>>(vw, Wvb, nW);
  cvt_f32_bf16<<<(nW / 4 + 255) / 256, 256, 0, stream>>>(ow, Wob, nW);

  // fused QKV projections: Q=(X Wq^T + bq)*0.125, K, V
  gemm_bt<true><<<dim3(32, 8, 3), 256, 0, stream>>>(
      Xb, Wqb, Wkb, Wvb, qb, kb, vb, Qb, Kb, Vb, 0.125f);

  attn_fwd<<<dim3(32, 32), 256, 0, stream>>>(Qb, Kb, Vb, mask, Cb);

  // output projection (fp32 out)
  gemm_bt<false><<<dim3(32, 8, 1), 256, 0, stream>>>(
      Cb, Wob, Wob, Wob, ob, ob, ob, out, out, out, 1.0f);
}